// Round 8
// baseline (187.211 us; speedup 1.0000x reference)
//
#include <hip/hip_runtime.h>
#include <hip/hip_bf16.h>
#include <hip/hip_cooperative_groups.h>

namespace cg = cooperative_groups;

#define H 256
#define R_N 256
#define F_N 1024
#define WC_ROWS 257   // 256 weight rows + 1 bias row

struct MonoParams {
    const float *rf, *ff;
    const float *r_w1, *r_b1, *r_w2, *r_b2;
    const float *f_w1, *f_b1, *f_w2, *f_b2;
    const float *a_w1, *a_b1, *a_w2, *a_b2;
    float *u, *v, *Wc, *out;
};

// ===========================================================================
// mono_kernel: ONE cooperative dispatch, 256 blocks x 512 threads (1/CU).
//  phase 1: Wc[p] = [W2_p; b2_p] @ w1_p  (+a_b1 on frontier bias row)
//  phase 2: u/v = relu(x@w1+b1) @ Wc     (160 active blocks, 8 rows each)
//  phase 3: affinity 32x32 tile per block (proven round-6/7 code)
// LDS 84.5 KB -> exactly 1 block/CU, all 256 blocks co-resident.
// ===========================================================================
__global__ __launch_bounds__(512, 1) void mono_kernel(MonoParams P)
{
    __shared__ float u_s[32][260];
    __shared__ float v_s[32][260];
    __shared__ float w_s[H];             // phase 1: A-row stage; phase 3: w2
    __shared__ float red[4][32][33];     // phase 1/2: partial bufs; phase 3: reduce

    const int t   = threadIdx.x;
    const int bid = blockIdx.x;
    cg::grid_group grid = cg::this_grid();

    // ---------------- Phase 1: combined weights Wc ----------------
    // global rows g in [0,514): p = g>=257, r = g - p*257.
    // block bid does g = 2*bid, 2*bid+1; blocks 0,1 also g = 512+bid.
    {
        float* p2 = &red[0][0][0];       // 2*256 floats
        const int c  = t & 255;
        const int kh = t >> 8;
        for (int sub = 0; sub < 3; ++sub) {
            if (sub == 2 && bid >= 2) break;
            const int g = (sub < 2) ? (bid * 2 + sub) : (512 + bid);
            const int p = (g >= WC_ROWS) ? 1 : 0;
            const int r = g - p * WC_ROWS;
            const float* __restrict__ W2 = p ? P.f_w2 : P.r_w2;
            const float* __restrict__ b2 = p ? P.f_b2 : P.r_b2;
            const float* __restrict__ w1 = P.a_w1 + p * H * H;
            __syncthreads();
            if (t < H) w_s[t] = (r < H) ? W2[r * H + t] : b2[t];
            __syncthreads();
            float acc = 0.0f;
            const int kb = kh * 128;
            #pragma unroll 8
            for (int kk = 0; kk < 128; ++kk) {
                const int k = kb + kk;
                acc = fmaf(w_s[k], w1[k * H + c], acc);
            }
            p2[kh * 256 + c] = acc;
            __syncthreads();
            if (t < H) {
                float s = p2[t] + p2[256 + t];
                if (r == H && p == 1) s += P.a_b1[t];
                P.Wc[(p * WC_ROWS + r) * H + t] = s;
            }
        }
    }
    __threadfence();
    grid.sync();

    // ---------------- Phase 2: u (rows 0..255), v (rows 0..1023) ----------
    // 160 active blocks x 8 rows. act stored transposed aT[k][8] (alias u_s).
    if (bid < 160) {
        const bool robot = bid < 32;
        const int  g0    = robot ? bid * 8 : (bid - 32) * 8;
        const float* __restrict__ x   = robot ? P.rf : P.ff;
        const float* __restrict__ w1  = robot ? P.r_w1 : P.f_w1;
        const float* __restrict__ b1  = robot ? P.r_b1 : P.f_b1;
        const int                 nd  = robot ? 4 : 3;
        const float* __restrict__ Wcb = P.Wc + (robot ? 0 : WC_ROWS * H);
        float* __restrict__       dst = robot ? P.u : P.v;

        float (*aT)[8] = (float(*)[8])&u_s[0][0];   // 256*8 floats
        float* p2 = &red[0][0][0];                  // 2*8*256 = 4096 floats

        {   // layer 1: thread (k0, gh) does rows gh*4..gh*4+3 at col k0
            const int k0 = t & 255;
            const int gh = (t >> 8) * 4;
            const float bb = b1[k0];
            float l[4];
            #pragma unroll
            for (int g = 0; g < 4; ++g) {
                float a = bb;
                for (int j = 0; j < nd; ++j)
                    a = fmaf(x[(g0 + gh + g) * nd + j], w1[j * H + k0], a);
                l[g] = fmaxf(a, 0.0f);
            }
            *(float4*)&aT[k0][gh] = make_float4(l[0], l[1], l[2], l[3]);
        }
        __syncthreads();

        const int c  = t & 255;
        const int kh = t >> 8;
        float4 accL = make_float4(0.f, 0.f, 0.f, 0.f);
        float4 accH = make_float4(0.f, 0.f, 0.f, 0.f);
        const int kb = kh * 128;
        #pragma unroll 4
        for (int kk = 0; kk < 128; ++kk) {
            const int k = kb + kk;
            const float  w   = Wcb[k * H + c];
            const float4 alo = *(const float4*)&aT[k][0];
            const float4 ahi = *(const float4*)&aT[k][4];
            accL.x = fmaf(alo.x, w, accL.x);
            accL.y = fmaf(alo.y, w, accL.y);
            accL.z = fmaf(alo.z, w, accL.z);
            accL.w = fmaf(alo.w, w, accL.w);
            accH.x = fmaf(ahi.x, w, accH.x);
            accH.y = fmaf(ahi.y, w, accH.y);
            accH.z = fmaf(ahi.z, w, accH.z);
            accH.w = fmaf(ahi.w, w, accH.w);
        }
        p2[(kh * 8 + 0) * 256 + c] = accL.x;
        p2[(kh * 8 + 1) * 256 + c] = accL.y;
        p2[(kh * 8 + 2) * 256 + c] = accL.z;
        p2[(kh * 8 + 3) * 256 + c] = accL.w;
        p2[(kh * 8 + 4) * 256 + c] = accH.x;
        p2[(kh * 8 + 5) * 256 + c] = accH.y;
        p2[(kh * 8 + 6) * 256 + c] = accH.z;
        p2[(kh * 8 + 7) * 256 + c] = accH.w;
        __syncthreads();
        {
            const int c2 = t & 255;
            const int g4 = (t >> 8) * 4;
            const float bias = Wcb[H * H + c2];   // bias row 256
            #pragma unroll
            for (int g = g4; g < g4 + 4; ++g) {
                const float s = p2[g * 256 + c2] + p2[(8 + g) * 256 + c2] + bias;
                dst[(g0 + g) * H + c2] = s;
            }
        }
    }
    __threadfence();
    grid.sync();

    // ---------------- Phase 3: affinity (proven round-6 tile) -------------
    {
        const int r0 = (bid >> 5) * 32;
        const int f0 = (bid & 31) * 32;

        #pragma unroll
        for (int i = 0; i < 4; ++i) {
            const int slot = t + i * 512;
            const int row  = slot >> 6;
            const int cc   = (slot & 63) * 4;
            *(float4*)&u_s[row][cc] = *(const float4*)&P.u[(r0 + row) * H + cc];
            *(float4*)&v_s[row][cc] = *(const float4*)&P.v[(f0 + row) * H + cc];
        }
        if (t < 64) *(float4*)&w_s[t * 4] = *(const float4*)&P.a_w2[t * 4];
        __syncthreads();

        const int kp = t >> 7;
        const int t7 = t & 127;
        const int ri = t7 >> 4;
        const int fi = t7 & 15;
        const int k0 = kp * 64;

        float4 accA = make_float4(0.f, 0.f, 0.f, 0.f);
        float4 accB = make_float4(0.f, 0.f, 0.f, 0.f);

        #pragma unroll 4
        for (int kk = 0; kk < 64; kk += 4) {
            const int k = k0 + kk;
            const float4 w4 = *(const float4*)&w_s[k];
            const float4 u0 = *(const float4*)&u_s[ri][k];
            const float4 u1 = *(const float4*)&u_s[ri +  8][k];
            const float4 u2 = *(const float4*)&u_s[ri + 16][k];
            const float4 u3 = *(const float4*)&u_s[ri + 24][k];
            const float4 va = *(const float4*)&v_s[fi][k];
            const float4 vb = *(const float4*)&v_s[fi + 16][k];

            accA.x = fmaf(fmaxf(u0.x + va.x, 0.f), w4.x, accA.x);
            accA.x = fmaf(fmaxf(u0.y + va.y, 0.f), w4.y, accA.x);
            accA.x = fmaf(fmaxf(u0.z + va.z, 0.f), w4.z, accA.x);
            accA.x = fmaf(fmaxf(u0.w + va.w, 0.f), w4.w, accA.x);
            accA.y = fmaf(fmaxf(u1.x + va.x, 0.f), w4.x, accA.y);
            accA.y = fmaf(fmaxf(u1.y + va.y, 0.f), w4.y, accA.y);
            accA.y = fmaf(fmaxf(u1.z + va.z, 0.f), w4.z, accA.y);
            accA.y = fmaf(fmaxf(u1.w + va.w, 0.f), w4.w, accA.y);
            accA.z = fmaf(fmaxf(u2.x + va.x, 0.f), w4.x, accA.z);
            accA.z = fmaf(fmaxf(u2.y + va.y, 0.f), w4.y, accA.z);
            accA.z = fmaf(fmaxf(u2.z + va.z, 0.f), w4.z, accA.z);
            accA.z = fmaf(fmaxf(u2.w + va.w, 0.f), w4.w, accA.z);
            accA.w = fmaf(fmaxf(u3.x + va.x, 0.f), w4.x, accA.w);
            accA.w = fmaf(fmaxf(u3.y + va.y, 0.f), w4.y, accA.w);
            accA.w = fmaf(fmaxf(u3.z + va.z, 0.f), w4.z, accA.w);
            accA.w = fmaf(fmaxf(u3.w + va.w, 0.f), w4.w, accA.w);

            accB.x = fmaf(fmaxf(u0.x + vb.x, 0.f), w4.x, accB.x);
            accB.x = fmaf(fmaxf(u0.y + vb.y, 0.f), w4.y, accB.x);
            accB.x = fmaf(fmaxf(u0.z + vb.z, 0.f), w4.z, accB.x);
            accB.x = fmaf(fmaxf(u0.w + vb.w, 0.f), w4.w, accB.x);
            accB.y = fmaf(fmaxf(u1.x + vb.x, 0.f), w4.x, accB.y);
            accB.y = fmaf(fmaxf(u1.y + vb.y, 0.f), w4.y, accB.y);
            accB.y = fmaf(fmaxf(u1.z + vb.z, 0.f), w4.z, accB.y);
            accB.y = fmaf(fmaxf(u1.w + vb.w, 0.f), w4.w, accB.y);
            accB.z = fmaf(fmaxf(u2.x + vb.x, 0.f), w4.x, accB.z);
            accB.z = fmaf(fmaxf(u2.y + vb.y, 0.f), w4.y, accB.z);
            accB.z = fmaf(fmaxf(u2.z + vb.z, 0.f), w4.z, accB.z);
            accB.z = fmaf(fmaxf(u2.w + vb.w, 0.f), w4.w, accB.z);
            accB.w = fmaf(fmaxf(u3.x + vb.x, 0.f), w4.x, accB.w);
            accB.w = fmaf(fmaxf(u3.y + vb.y, 0.f), w4.y, accB.w);
            accB.w = fmaf(fmaxf(u3.z + vb.z, 0.f), w4.z, accB.w);
            accB.w = fmaf(fmaxf(u3.w + vb.w, 0.f), w4.w, accB.w);
        }

        red[kp][ri]     [fi]      = accA.x;
        red[kp][ri +  8][fi]      = accA.y;
        red[kp][ri + 16][fi]      = accA.z;
        red[kp][ri + 24][fi]      = accA.w;
        red[kp][ri]     [fi + 16] = accB.x;
        red[kp][ri +  8][fi + 16] = accB.y;
        red[kp][ri + 16][fi + 16] = accB.z;
        red[kp][ri + 24][fi + 16] = accB.w;
        __syncthreads();

        const float b = P.a_b2[0];
        #pragma unroll
        for (int j = 0; j < 2; ++j) {
            const int o = t + j * 512;
            const int r = o >> 5;
            const int f = o & 31;
            const float s = red[0][r][f] + red[1][r][f] + red[2][r][f] + red[3][r][f] + b;
            P.out[(r0 + r) * F_N + f0 + f] = s;
        }
    }
}

// ===========================================================================
// FALLBACK: proven round-7 3-kernel path (used only if cooperative launch
// is rejected, e.g. by graph capture).
// ===========================================================================
__global__ __launch_bounds__(256) void combine_kernel(
    const float* __restrict__ r_w2, const float* __restrict__ r_b2,
    const float* __restrict__ f_w2, const float* __restrict__ f_b2,
    const float* __restrict__ a_w1, const float* __restrict__ a_b1,
    float* __restrict__ Wc)
{
    __shared__ float aT[H][12];
    __shared__ float red[4][8][40];

    const int t    = threadIdx.x;
    const int b    = blockIdx.x;
    const int p    = b / 264;
    const int rem  = b % 264;
    const int rt   = rem >> 3;
    const int ct   = rem & 7;
    const int i0   = rt * 8;
    const int col0 = ct * 32;

    const float* __restrict__ W2  = p ? f_w2 : r_w2;
    const float* __restrict__ b2  = p ? f_b2 : r_b2;
    const float* __restrict__ w1  = a_w1 + p * H * H;
    float* __restrict__       out = Wc + p * WC_ROWS * H;

    {
        float vb[8];
        #pragma unroll
        for (int g = 0; g < 8; ++g) {
            const int i = i0 + g;
            vb[g] = (i < H) ? W2[i * H + t] : ((i == H) ? b2[t] : 0.0f);
        }
        *(float4*)&aT[t][0] = make_float4(vb[0], vb[1], vb[2], vb[3]);
        *(float4*)&aT[t][4] = make_float4(vb[4], vb[5], vb[6], vb[7]);
    }
    __syncthreads();

    const int kp  = t >> 6;
    const int idx = t & 63;
    const int r   = idx >> 3;
    const int cl  = (idx & 7) * 4;

    float4 acc = make_float4(0.f, 0.f, 0.f, 0.f);
    const int kb = kp * 64;
    #pragma unroll 8
    for (int kk = 0; kk < 64; ++kk) {
        const int k = kb + kk;
        const float4 w4 = *(const float4*)&w1[k * H + col0 + cl];
        const float  a  = aT[k][r];
        acc.x = fmaf(a, w4.x, acc.x);
        acc.y = fmaf(a, w4.y, acc.y);
        acc.z = fmaf(a, w4.z, acc.z);
        acc.w = fmaf(a, w4.w, acc.w);
    }
    *(float4*)&red[kp][r][cl] = acc;
    __syncthreads();

    const int rr = t >> 5;
    const int cc = t & 31;
    const int i  = i0 + rr;
    if (i < WC_ROWS) {
        float s = red[0][rr][cc] + red[1][rr][cc] + red[2][rr][cc] + red[3][rr][cc];
        if (i == H && p == 1) s += a_b1[col0 + cc];
        out[i * H + col0 + cc] = s;
    }
}

__global__ __launch_bounds__(256) void fused_uv_kernel(
    const float* __restrict__ rf, const float* __restrict__ ff,
    const float* __restrict__ r_w1, const float* __restrict__ r_b1,
    const float* __restrict__ f_w1, const float* __restrict__ f_b1,
    const float* __restrict__ Wc,
    float* __restrict__ u, float* __restrict__ v)
{
    __shared__ float aT[H][12];
    __shared__ float red[4][8][40];

    const int t    = threadIdx.x;
    const int rt   = blockIdx.x >> 3;
    const int ct   = blockIdx.x & 7;
    const bool robot = rt < 32;
    const int g0   = robot ? rt * 8 : (rt - 32) * 8;
    const int col0 = ct * 32;
    const float* __restrict__ Wcb = Wc + (robot ? 0 : WC_ROWS * H);

    {
        const float* __restrict__ x  = robot ? rf : ff;
        const float* __restrict__ w1 = robot ? r_w1 : f_w1;
        const float bb = (robot ? r_b1 : f_b1)[t];
        const int   nd = robot ? 4 : 3;
        float l[8];
        #pragma unroll
        for (int g = 0; g < 8; ++g) {
            float acc = bb;
            for (int j = 0; j < nd; ++j)
                acc = fmaf(x[(g0 + g) * nd + j], w1[j * H + t], acc);
            l[g] = fmaxf(acc, 0.0f);
        }
        *(float4*)&aT[t][0] = make_float4(l[0], l[1], l[2], l[3]);
        *(float4*)&aT[t][4] = make_float4(l[4], l[5], l[6], l[7]);
    }
    __syncthreads();

    const int kp  = t >> 6;
    const int idx = t & 63;
    const int r   = idx >> 3;
    const int cl  = (idx & 7) * 4;

    float4 acc = make_float4(0.f, 0.f, 0.f, 0.f);
    const int kb = kp * 64;
    #pragma unroll 8
    for (int kk = 0; kk < 64; ++kk) {
        const int k = kb + kk;
        const float4 w4 = *(const float4*)&Wcb[k * H + col0 + cl];
        const float  a  = aT[k][r];
        acc.x = fmaf(a, w4.x, acc.x);
        acc.y = fmaf(a, w4.y, acc.y);
        acc.z = fmaf(a, w4.z, acc.z);
        acc.w = fmaf(a, w4.w, acc.w);
    }
    *(float4*)&red[kp][r][cl] = acc;
    __syncthreads();

    const int rr  = t >> 5;
    const int cc  = t & 31;
    const int col = col0 + cc;
    float s = red[0][rr][cc] + red[1][rr][cc] + red[2][rr][cc] + red[3][rr][cc]
            + Wcb[H * H + col];
    if (robot) u[(g0 + rr) * H + col] = s;
    else       v[(g0 + rr) * H + col] = s;
}

#define LDP 260

__global__ __launch_bounds__(512) void affinity_kernel(
    const float* __restrict__ u, const float* __restrict__ v,
    const float* __restrict__ a_w2, const float* __restrict__ a_b2,
    float* __restrict__ out)
{
    __shared__ float u_s[32][LDP];
    __shared__ float v_s[32][LDP];
    __shared__ float w_s[H];
    __shared__ float red[4][32][33];

    const int t  = threadIdx.x;
    const int r0 = (blockIdx.x >> 5) * 32;
    const int f0 = (blockIdx.x & 31) * 32;

    #pragma unroll
    for (int i = 0; i < 4; ++i) {
        const int slot = t + i * 512;
        const int row  = slot >> 6;
        const int cc   = (slot & 63) * 4;
        *(float4*)&u_s[row][cc] = *(const float4*)&u[(r0 + row) * H + cc];
        *(float4*)&v_s[row][cc] = *(const float4*)&v[(f0 + row) * H + cc];
    }
    if (t < 64) *(float4*)&w_s[t * 4] = *(const float4*)&a_w2[t * 4];
    __syncthreads();

    const int kp = t >> 7;
    const int t7 = t & 127;
    const int ri = t7 >> 4;
    const int fi = t7 & 15;
    const int k0 = kp * 64;

    float4 accA = make_float4(0.f, 0.f, 0.f, 0.f);
    float4 accB = make_float4(0.f, 0.f, 0.f, 0.f);

    #pragma unroll 4
    for (int kk = 0; kk < 64; kk += 4) {
        const int k = k0 + kk;
        const float4 w4 = *(const float4*)&w_s[k];
        const float4 u0 = *(const float4*)&u_s[ri][k];
        const float4 u1 = *(const float4*)&u_s[ri +  8][k];
        const float4 u2 = *(const float4*)&u_s[ri + 16][k];
        const float4 u3 = *(const float4*)&u_s[ri + 24][k];
        const float4 va = *(const float4*)&v_s[fi][k];
        const float4 vb = *(const float4*)&v_s[fi + 16][k];

        accA.x = fmaf(fmaxf(u0.x + va.x, 0.f), w4.x, accA.x);
        accA.x = fmaf(fmaxf(u0.y + va.y, 0.f), w4.y, accA.x);
        accA.x = fmaf(fmaxf(u0.z + va.z, 0.f), w4.z, accA.x);
        accA.x = fmaf(fmaxf(u0.w + va.w, 0.f), w4.w, accA.x);
        accA.y = fmaf(fmaxf(u1.x + va.x, 0.f), w4.x, accA.y);
        accA.y = fmaf(fmaxf(u1.y + va.y, 0.f), w4.y, accA.y);
        accA.y = fmaf(fmaxf(u1.z + va.z, 0.f), w4.z, accA.y);
        accA.y = fmaf(fmaxf(u1.w + va.w, 0.f), w4.w, accA.y);
        accA.z = fmaf(fmaxf(u2.x + va.x, 0.f), w4.x, accA.z);
        accA.z = fmaf(fmaxf(u2.y + va.y, 0.f), w4.y, accA.z);
        accA.z = fmaf(fmaxf(u2.z + va.z, 0.f), w4.z, accA.z);
        accA.z = fmaf(fmaxf(u2.w + va.w, 0.f), w4.w, accA.z);
        accA.w = fmaf(fmaxf(u3.x + va.x, 0.f), w4.x, accA.w);
        accA.w = fmaf(fmaxf(u3.y + va.y, 0.f), w4.y, accA.w);
        accA.w = fmaf(fmaxf(u3.z + va.z, 0.f), w4.z, accA.w);
        accA.w = fmaf(fmaxf(u3.w + va.w, 0.f), w4.w, accA.w);

        accB.x = fmaf(fmaxf(u0.x + vb.x, 0.f), w4.x, accB.x);
        accB.x = fmaf(fmaxf(u0.y + vb.y, 0.f), w4.y, accB.x);
        accB.x = fmaf(fmaxf(u0.z + vb.z, 0.f), w4.z, accB.x);
        accB.x = fmaf(fmaxf(u0.w + vb.w, 0.f), w4.w, accB.x);
        accB.y = fmaf(fmaxf(u1.x + vb.x, 0.f), w4.x, accB.y);
        accB.y = fmaf(fmaxf(u1.y + vb.y, 0.f), w4.y, accB.y);
        accB.y = fmaf(fmaxf(u1.z + vb.z, 0.f), w4.z, accB.y);
        accB.y = fmaf(fmaxf(u1.w + vb.w, 0.f), w4.w, accB.y);
        accB.z = fmaf(fmaxf(u2.x + vb.x, 0.f), w4.x, accB.z);
        accB.z = fmaf(fmaxf(u2.y + vb.y, 0.f), w4.y, accB.z);
        accB.z = fmaf(fmaxf(u2.z + vb.z, 0.f), w4.z, accB.z);
        accB.z = fmaf(fmaxf(u2.w + vb.w, 0.f), w4.w, accB.z);
        accB.w = fmaf(fmaxf(u3.x + vb.x, 0.f), w4.x, accB.w);
        accB.w = fmaf(fmaxf(u3.y + vb.y, 0.f), w4.y, accB.w);
        accB.w = fmaf(fmaxf(u3.z + vb.z, 0.f), w4.z, accB.w);
        accB.w = fmaf(fmaxf(u3.w + vb.w, 0.f), w4.w, accB.w);
    }

    red[kp][ri]     [fi]      = accA.x;
    red[kp][ri +  8][fi]      = accA.y;
    red[kp][ri + 16][fi]      = accA.z;
    red[kp][ri + 24][fi]      = accA.w;
    red[kp][ri]     [fi + 16] = accB.x;
    red[kp][ri +  8][fi + 16] = accB.y;
    red[kp][ri + 16][fi + 16] = accB.z;
    red[kp][ri + 24][fi + 16] = accB.w;
    __syncthreads();

    const float b = a_b2[0];
    #pragma unroll
    for (int j = 0; j < 2; ++j) {
        const int o = t + j * 512;
        const int r = o >> 5;
        const int f = o & 31;
        const float s = red[0][r][f] + red[1][r][f] + red[2][r][f] + red[3][r][f] + b;
        out[(r0 + r) * F_N + f0 + f] = s;
    }
}

extern "C" void kernel_launch(void* const* d_in, const int* in_sizes, int n_in,
                              void* d_out, int out_size, void* d_ws, size_t ws_size,
                              hipStream_t stream) {
    const float* rf   = (const float*)d_in[0];
    const float* ff   = (const float*)d_in[1];
    const float* r_w1 = (const float*)d_in[2];
    const float* r_b1 = (const float*)d_in[3];
    const float* r_w2 = (const float*)d_in[4];
    const float* r_b2 = (const float*)d_in[5];
    const float* f_w1 = (const float*)d_in[6];
    const float* f_b1 = (const float*)d_in[7];
    const float* f_w2 = (const float*)d_in[8];
    const float* f_b2 = (const float*)d_in[9];
    const float* a_w1 = (const float*)d_in[10];
    const float* a_b1 = (const float*)d_in[11];
    const float* a_w2 = (const float*)d_in[12];
    const float* a_b2 = (const float*)d_in[13];

    float* u  = (float*)d_ws;                  // 256*256
    float* v  = u + R_N * H;                   // 1024*256
    float* Wc = v + F_N * H;                   // 2*257*256  (total 1.75 MB, proven)

    MonoParams P;
    P.rf = rf; P.ff = ff;
    P.r_w1 = r_w1; P.r_b1 = r_b1; P.r_w2 = r_w2; P.r_b2 = r_b2;
    P.f_w1 = f_w1; P.f_b1 = f_b1; P.f_w2 = f_w2; P.f_b2 = f_b2;
    P.a_w1 = a_w1; P.a_b1 = a_b1; P.a_w2 = a_w2; P.a_b2 = a_b2;
    P.u = u; P.v = v; P.Wc = Wc; P.out = (float*)d_out;

    void* args[] = { (void*)&P };
    hipError_t err = hipLaunchCooperativeKernel((const void*)mono_kernel,
                                                dim3(256), dim3(512),
                                                args, 0, stream);
    if (err != hipSuccess) {
        // Fallback: proven round-7 3-kernel path.
        combine_kernel<<<528, 256, 0, stream>>>(r_w2, r_b2, f_w2, f_b2,
                                                a_w1, a_b1, Wc);
        fused_uv_kernel<<<1280, 256, 0, stream>>>(rf, ff, r_w1, r_b1,
                                                  f_w1, f_b1, Wc, u, v);
        affinity_kernel<<<256, 512, 0, stream>>>(u, v, a_w2, a_b2, (float*)d_out);
    }
}

// Round 9
// 40.983 us; speedup vs baseline: 4.5680x; 4.5680x over previous
//
#include <hip/hip_runtime.h>
#include <hip/hip_bf16.h>

#define H 256
#define R_N 256
#define F_N 1024

#define FMA4V(A, s, W) \
    A.x = fmaf((s), (W).x, A.x); \
    A.y = fmaf((s), (W).y, A.y); \
    A.z = fmaf((s), (W).z, A.z); \
    A.w = fmaf((s), (W).w, A.w);

// ---------------------------------------------------------------------------
// K1 uv_kernel: fused {Wc column-slice} + {u/v rows} — NO grid sync needed.
//   Wc[k][c] = sum_j A[k][j] * w1p[j][c],  A = [W2p ; b2p]  (257 rows)
//   u/v[g][c] = sum_k relu(x[g]@w1L[:,k]+b1L[k]) * Wc[k][c] + Wc[256][c]
// Grid: 320 = 64 col-slices (4 cols) x 5 row-groups (rg0 = robot 256 rows,
// rg1..4 = frontier 256 rows each). 512 threads: g = t&63 (4 rows),
// kh = t>>6 (8-way j/k split, register-accumulated, LDS-reduced at the end).
// Redundancy: Wc_r x1, Wc_f x4 => ~170 MF total (vs 33 ideal) — cheap.
// LDS ~70 KB -> 2 blocks/CU. Grid-sync lesson from round 8: fuse via
// per-block recompute, never via cooperative barriers (75 us/sync on 8 XCDs).
// ---------------------------------------------------------------------------
__global__ __launch_bounds__(512, 4) void uv_kernel(
    const float* __restrict__ rf, const float* __restrict__ ff,
    const float* __restrict__ r_w1, const float* __restrict__ r_b1,
    const float* __restrict__ r_w2, const float* __restrict__ r_b2,
    const float* __restrict__ f_w1, const float* __restrict__ f_b1,
    const float* __restrict__ f_w2, const float* __restrict__ f_b2,
    const float* __restrict__ a_w1, const float* __restrict__ a_b1,
    float* __restrict__ u, float* __restrict__ v)
{
    __shared__ float Pt[32][260];      // A-chunk transposed [j][row 0..256]
    __shared__ float w1q[256][4];      // w1p[:, c0..c0+3]
    __shared__ float Wq[8][257][4];    // kh-partials; final Wc slice in Wq[0]

    const int t  = threadIdx.x;
    const int cs = blockIdx.x & 63;
    const int rg = blockIdx.x >> 6;
    const int c0 = cs * 4;
    const bool robot   = (rg == 0);
    const int  p       = robot ? 0 : 1;
    const int  rowbase = robot ? 0 : (rg - 1) * 256;

    const float* __restrict__ W2p = robot ? r_w2 : f_w2;
    const float* __restrict__ b2p = robot ? r_b2 : f_b2;
    const float* __restrict__ w1p = a_w1 + p * H * H;
    const float* __restrict__ w1L = robot ? r_w1 : f_w1;
    const float* __restrict__ b1L = robot ? r_b1 : f_b1;
    const int nd = robot ? 4 : 3;
    float* __restrict__ dst = robot ? u : (v + rowbase * H);

    const int g  = t & 63;     // row group: rows 4g..4g+3
    const int kh = t >> 6;     // j/k part 0..7

    // ================= Phase 1: Wc slice =================
    float4 acc0 = {0,0,0,0}, acc1 = {0,0,0,0}, acc2 = {0,0,0,0}, acc3 = {0,0,0,0};
    float4 accB = {0,0,0,0};   // bias row, g==63 threads only

    for (int ci = 0; ci < 8; ++ci) {
        if (ci) __syncthreads();                 // prior compute done with Pt
        const int jb = ci * 32;
        for (int slot = t; slot < 257 * 32; slot += 512) {
            const int r = slot >> 5, j = slot & 31;
            Pt[j][r] = (r < H) ? W2p[r * H + jb + j] : b2p[jb + j];
        }
        if (ci == 0) {
            for (int s = t; s < 1024; s += 512)
                w1q[s >> 2][s & 3] = w1p[(s >> 2) * H + c0 + (s & 3)];
        }
        __syncthreads();
        #pragma unroll
        for (int jo = 0; jo < 4; ++jo) {
            const int jl = kh * 4 + jo;
            const float4 pa = *(const float4*)&Pt[jl][4 * g];
            const float4 wq = *(const float4*)&w1q[jb + jl][0];
            FMA4V(acc0, pa.x, wq);
            FMA4V(acc1, pa.y, wq);
            FMA4V(acc2, pa.z, wq);
            FMA4V(acc3, pa.w, wq);
            if (g == 63) { const float pb = Pt[jl][256]; FMA4V(accB, pb, wq); }
        }
    }
    __syncthreads();
    *(float4*)&Wq[kh][4 * g + 0][0] = acc0;
    *(float4*)&Wq[kh][4 * g + 1][0] = acc1;
    *(float4*)&Wq[kh][4 * g + 2][0] = acc2;
    *(float4*)&Wq[kh][4 * g + 3][0] = acc3;
    if (g == 63) *(float4*)&Wq[kh][256][0] = accB;
    __syncthreads();

    // finalize Wc slice into Wq[0]; stage layer-1 weights into Pt space
    for (int s = t; s < 257; s += 512) {
        float sx = 0.f, sy = 0.f, sz = 0.f, sw = 0.f;
        #pragma unroll
        for (int q = 0; q < 8; ++q) {
            sx += Wq[q][s][0]; sy += Wq[q][s][1];
            sz += Wq[q][s][2]; sw += Wq[q][s][3];
        }
        if (s == H && p == 1) {
            sx += a_b1[c0]; sy += a_b1[c0 + 1]; sz += a_b1[c0 + 2]; sw += a_b1[c0 + 3];
        }
        Wq[0][s][0] = sx; Wq[0][s][1] = sy; Wq[0][s][2] = sz; Wq[0][s][3] = sw;
    }
    float* L = &Pt[0][0];                       // [nd+1][256]: w1L rows then b1L
    for (int s = t; s < (nd + 1) * 256; s += 512)
        L[s] = (s < nd * 256) ? w1L[s] : b1L[s - nd * 256];

    // x rows into registers (rows 4g..4g+3 of this row-group)
    float xr[4][4];
    #pragma unroll
    for (int r = 0; r < 4; ++r) {
        const int grow = rowbase + 4 * g + r;
        if (robot) {
            const float4 xv = *(const float4*)&rf[(4 * g + r) * 4];
            xr[r][0] = xv.x; xr[r][1] = xv.y; xr[r][2] = xv.z; xr[r][3] = xv.w;
        } else {
            xr[r][0] = ff[grow * 3 + 0];
            xr[r][1] = ff[grow * 3 + 1];
            xr[r][2] = ff[grow * 3 + 2];
            xr[r][3] = 0.0f;
        }
    }
    __syncthreads();                            // Wq[0] final + L ready

    // ================= Phase 2: u/v rows =================
    float4 ua0 = {0,0,0,0}, ua1 = {0,0,0,0}, ua2 = {0,0,0,0}, ua3 = {0,0,0,0};
    const int kb = kh * 32;
    #pragma unroll 4
    for (int k = kb; k < kb + 32; ++k) {
        const float w0 = L[k];
        const float w1_ = L[256 + k];
        const float w2_ = L[512 + k];
        const float w3_ = robot ? L[768 + k] : 0.0f;
        const float bb  = robot ? L[1024 + k] : L[768 + k];
        const float4 wc = *(const float4*)&Wq[0][k][0];
        float a0 = fmaf(xr[0][0], w0, fmaf(xr[0][1], w1_, fmaf(xr[0][2], w2_, fmaf(xr[0][3], w3_, bb))));
        float a1 = fmaf(xr[1][0], w0, fmaf(xr[1][1], w1_, fmaf(xr[1][2], w2_, fmaf(xr[1][3], w3_, bb))));
        float a2 = fmaf(xr[2][0], w0, fmaf(xr[2][1], w1_, fmaf(xr[2][2], w2_, fmaf(xr[2][3], w3_, bb))));
        float a3 = fmaf(xr[3][0], w0, fmaf(xr[3][1], w1_, fmaf(xr[3][2], w2_, fmaf(xr[3][3], w3_, bb))));
        a0 = fmaxf(a0, 0.f); a1 = fmaxf(a1, 0.f); a2 = fmaxf(a2, 0.f); a3 = fmaxf(a3, 0.f);
        FMA4V(ua0, a0, wc);
        FMA4V(ua1, a1, wc);
        FMA4V(ua2, a2, wc);
        FMA4V(ua3, a3, wc);
    }
    __syncthreads();                            // everyone done reading Wq[0] rows
    *(float4*)&Wq[kh][4 * g + 0][0] = ua0;      // rows 0..255 only; bias row intact
    *(float4*)&Wq[kh][4 * g + 1][0] = ua1;
    *(float4*)&Wq[kh][4 * g + 2][0] = ua2;
    *(float4*)&Wq[kh][4 * g + 3][0] = ua3;
    __syncthreads();
    if (t < 256) {
        float sx = Wq[0][256][0], sy = Wq[0][256][1], sz = Wq[0][256][2], sw = Wq[0][256][3];
        #pragma unroll
        for (int q = 0; q < 8; ++q) {
            sx += Wq[q][t][0]; sy += Wq[q][t][1];
            sz += Wq[q][t][2]; sw += Wq[q][t][3];
        }
        float4 o; o.x = sx; o.y = sy; o.z = sz; o.w = sw;
        *(float4*)&dst[t * H + c0] = o;
    }
}

// ---------------------------------------------------------------------------
// K2 affinity (byte-identical to proven round-6/7 kernel):
// out[r,f] = sum_k relu(u[r,k]+v[f,k])*w2[k] + b2
// ---------------------------------------------------------------------------
#define LDP 260

__global__ __launch_bounds__(512) void affinity_kernel(
    const float* __restrict__ u, const float* __restrict__ v,
    const float* __restrict__ a_w2, const float* __restrict__ a_b2,
    float* __restrict__ out)
{
    __shared__ float u_s[32][LDP];
    __shared__ float v_s[32][LDP];
    __shared__ float w_s[H];
    __shared__ float red[4][32][33];

    const int t  = threadIdx.x;
    const int r0 = (blockIdx.x >> 5) * 32;
    const int f0 = (blockIdx.x & 31) * 32;

    #pragma unroll
    for (int i = 0; i < 4; ++i) {
        const int slot = t + i * 512;
        const int row  = slot >> 6;
        const int cc   = (slot & 63) * 4;
        *(float4*)&u_s[row][cc] = *(const float4*)&u[(r0 + row) * H + cc];
        *(float4*)&v_s[row][cc] = *(const float4*)&v[(f0 + row) * H + cc];
    }
    if (t < 64) *(float4*)&w_s[t * 4] = *(const float4*)&a_w2[t * 4];
    __syncthreads();

    const int kp = t >> 7;
    const int t7 = t & 127;
    const int ri = t7 >> 4;
    const int fi = t7 & 15;
    const int k0 = kp * 64;

    float4 accA = make_float4(0.f, 0.f, 0.f, 0.f);
    float4 accB = make_float4(0.f, 0.f, 0.f, 0.f);

    #pragma unroll 4
    for (int kk = 0; kk < 64; kk += 4) {
        const int k = k0 + kk;
        const float4 w4 = *(const float4*)&w_s[k];
        const float4 u0 = *(const float4*)&u_s[ri][k];
        const float4 u1 = *(const float4*)&u_s[ri +  8][k];
        const float4 u2 = *(const float4*)&u_s[ri + 16][k];
        const float4 u3 = *(const float4*)&u_s[ri + 24][k];
        const float4 va = *(const float4*)&v_s[fi][k];
        const float4 vb = *(const float4*)&v_s[fi + 16][k];

        accA.x = fmaf(fmaxf(u0.x + va.x, 0.f), w4.x, accA.x);
        accA.x = fmaf(fmaxf(u0.y + va.y, 0.f), w4.y, accA.x);
        accA.x = fmaf(fmaxf(u0.z + va.z, 0.f), w4.z, accA.x);
        accA.x = fmaf(fmaxf(u0.w + va.w, 0.f), w4.w, accA.x);
        accA.y = fmaf(fmaxf(u1.x + va.x, 0.f), w4.x, accA.y);
        accA.y = fmaf(fmaxf(u1.y + va.y, 0.f), w4.y, accA.y);
        accA.y = fmaf(fmaxf(u1.z + va.z, 0.f), w4.z, accA.y);
        accA.y = fmaf(fmaxf(u1.w + va.w, 0.f), w4.w, accA.y);
        accA.z = fmaf(fmaxf(u2.x + va.x, 0.f), w4.x, accA.z);
        accA.z = fmaf(fmaxf(u2.y + va.y, 0.f), w4.y, accA.z);
        accA.z = fmaf(fmaxf(u2.z + va.z, 0.f), w4.z, accA.z);
        accA.z = fmaf(fmaxf(u2.w + va.w, 0.f), w4.w, accA.z);
        accA.w = fmaf(fmaxf(u3.x + va.x, 0.f), w4.x, accA.w);
        accA.w = fmaf(fmaxf(u3.y + va.y, 0.f), w4.y, accA.w);
        accA.w = fmaf(fmaxf(u3.z + va.z, 0.f), w4.z, accA.w);
        accA.w = fmaf(fmaxf(u3.w + va.w, 0.f), w4.w, accA.w);

        accB.x = fmaf(fmaxf(u0.x + vb.x, 0.f), w4.x, accB.x);
        accB.x = fmaf(fmaxf(u0.y + vb.y, 0.f), w4.y, accB.x);
        accB.x = fmaf(fmaxf(u0.z + vb.z, 0.f), w4.z, accB.x);
        accB.x = fmaf(fmaxf(u0.w + vb.w, 0.f), w4.w, accB.x);
        accB.y = fmaf(fmaxf(u1.x + vb.x, 0.f), w4.x, accB.y);
        accB.y = fmaf(fmaxf(u1.y + vb.y, 0.f), w4.y, accB.y);
        accB.y = fmaf(fmaxf(u1.z + vb.z, 0.f), w4.z, accB.y);
        accB.y = fmaf(fmaxf(u1.w + vb.w, 0.f), w4.w, accB.y);
        accB.z = fmaf(fmaxf(u2.x + vb.x, 0.f), w4.x, accB.z);
        accB.z = fmaf(fmaxf(u2.y + vb.y, 0.f), w4.y, accB.z);
        accB.z = fmaf(fmaxf(u2.z + vb.z, 0.f), w4.z, accB.z);
        accB.z = fmaf(fmaxf(u2.w + vb.w, 0.f), w4.w, accB.z);
        accB.w = fmaf(fmaxf(u3.x + vb.x, 0.f), w4.x, accB.w);
        accB.w = fmaf(fmaxf(u3.y + vb.y, 0.f), w4.y, accB.w);
        accB.w = fmaf(fmaxf(u3.z + vb.z, 0.f), w4.z, accB.w);
        accB.w = fmaf(fmaxf(u3.w + vb.w, 0.f), w4.w, accB.w);
    }

    red[kp][ri]     [fi]      = accA.x;
    red[kp][ri +  8][fi]      = accA.y;
    red[kp][ri + 16][fi]      = accA.z;
    red[kp][ri + 24][fi]      = accA.w;
    red[kp][ri]     [fi + 16] = accB.x;
    red[kp][ri +  8][fi + 16] = accB.y;
    red[kp][ri + 16][fi + 16] = accB.z;
    red[kp][ri + 24][fi + 16] = accB.w;
    __syncthreads();

    const float b = a_b2[0];
    #pragma unroll
    for (int j = 0; j < 2; ++j) {
        const int o = t + j * 512;
        const int r = o >> 5;
        const int f = o & 31;
        const float s = red[0][r][f] + red[1][r][f] + red[2][r][f] + red[3][r][f] + b;
        out[(r0 + r) * F_N + f0 + f] = s;
    }
}

extern "C" void kernel_launch(void* const* d_in, const int* in_sizes, int n_in,
                              void* d_out, int out_size, void* d_ws, size_t ws_size,
                              hipStream_t stream) {
    const float* rf   = (const float*)d_in[0];
    const float* ff   = (const float*)d_in[1];
    const float* r_w1 = (const float*)d_in[2];
    const float* r_b1 = (const float*)d_in[3];
    const float* r_w2 = (const float*)d_in[4];
    const float* r_b2 = (const float*)d_in[5];
    const float* f_w1 = (const float*)d_in[6];
    const float* f_b1 = (const float*)d_in[7];
    const float* f_w2 = (const float*)d_in[8];
    const float* f_b2 = (const float*)d_in[9];
    const float* a_w1 = (const float*)d_in[10];
    const float* a_b1 = (const float*)d_in[11];
    const float* a_w2 = (const float*)d_in[12];
    const float* a_b2 = (const float*)d_in[13];

    float* u = (float*)d_ws;                 // 256*256 f32
    float* v = u + R_N * H;                  // 1024*256 f32  (1.31 MB total)

    uv_kernel<<<320, 512, 0, stream>>>(rf, ff, r_w1, r_b1, r_w2, r_b2,
                                       f_w1, f_b1, f_w2, f_b2,
                                       a_w1, a_b1, u, v);
    affinity_kernel<<<256, 512, 0, stream>>>(u, v, a_w2, a_b2, (float*)d_out);
}

// Round 11
// 29.609 us; speedup vs baseline: 6.3227x; 1.3841x over previous
//
#include <hip/hip_runtime.h>
#include <hip/hip_bf16.h>

#define H 256
#define R_N 256
#define F_N 1024

// ---------------------------------------------------------------------------
// embed (EXACT round-1 structure — the measured-best embed, 31.0 us config):
// 320 blocks x 256 threads, 4 rows/block. Per k-iter the wave reads a
// coalesced 256B weight segment; activations broadcast from LDS.
// ---------------------------------------------------------------------------
__global__ __launch_bounds__(256) void embed_kernel(
    const float* __restrict__ rf, const float* __restrict__ ff,
    const float* __restrict__ r_w1, const float* __restrict__ r_b1,
    const float* __restrict__ r_w2, const float* __restrict__ r_b2,
    const float* __restrict__ f_w1, const float* __restrict__ f_b1,
    const float* __restrict__ f_w2, const float* __restrict__ f_b2,
    const float* __restrict__ a_w1, const float* __restrict__ a_b1,
    float* __restrict__ u, float* __restrict__ v)
{
    const int t = threadIdx.x;
    __shared__ float a_s[4][H];
    __shared__ float e_s[4][H];

    if (blockIdx.x < 64) {
        const int r0 = blockIdx.x * 4;
        #pragma unroll
        for (int g = 0; g < 4; ++g) {
            const int r = r0 + g;
            float acc = r_b1[t];
            acc = fmaf(rf[r * 4 + 0], r_w1[0 * H + t], acc);
            acc = fmaf(rf[r * 4 + 1], r_w1[1 * H + t], acc);
            acc = fmaf(rf[r * 4 + 2], r_w1[2 * H + t], acc);
            acc = fmaf(rf[r * 4 + 3], r_w1[3 * H + t], acc);
            a_s[g][t] = fmaxf(acc, 0.0f);
        }
        __syncthreads();

        float e0 = r_b2[t], e1 = e0, e2 = e0, e3 = e0;
        #pragma unroll 8
        for (int k = 0; k < H; ++k) {
            const float w = r_w2[k * H + t];
            e0 = fmaf(a_s[0][k], w, e0);
            e1 = fmaf(a_s[1][k], w, e1);
            e2 = fmaf(a_s[2][k], w, e2);
            e3 = fmaf(a_s[3][k], w, e3);
        }
        __syncthreads();
        e_s[0][t] = e0; e_s[1][t] = e1; e_s[2][t] = e2; e_s[3][t] = e3;
        __syncthreads();

        float u0 = 0.f, u1 = 0.f, u2 = 0.f, u3 = 0.f;
        #pragma unroll 8
        for (int n = 0; n < H; ++n) {
            const float w = a_w1[n * H + t];
            u0 = fmaf(e_s[0][n], w, u0);
            u1 = fmaf(e_s[1][n], w, u1);
            u2 = fmaf(e_s[2][n], w, u2);
            u3 = fmaf(e_s[3][n], w, u3);
        }
        u[(r0 + 0) * H + t] = u0;
        u[(r0 + 1) * H + t] = u1;
        u[(r0 + 2) * H + t] = u2;
        u[(r0 + 3) * H + t] = u3;
    } else {
        const int f0 = (blockIdx.x - 64) * 4;
        #pragma unroll
        for (int g = 0; g < 4; ++g) {
            const int f = f0 + g;
            float acc = f_b1[t];
            acc = fmaf(ff[f * 3 + 0], f_w1[0 * H + t], acc);
            acc = fmaf(ff[f * 3 + 1], f_w1[1 * H + t], acc);
            acc = fmaf(ff[f * 3 + 2], f_w1[2 * H + t], acc);
            a_s[g][t] = fmaxf(acc, 0.0f);
        }
        __syncthreads();

        float e0 = f_b2[t], e1 = e0, e2 = e0, e3 = e0;
        #pragma unroll 8
        for (int k = 0; k < H; ++k) {
            const float w = f_w2[k * H + t];
            e0 = fmaf(a_s[0][k], w, e0);
            e1 = fmaf(a_s[1][k], w, e1);
            e2 = fmaf(a_s[2][k], w, e2);
            e3 = fmaf(a_s[3][k], w, e3);
        }
        __syncthreads();
        e_s[0][t] = e0; e_s[1][t] = e1; e_s[2][t] = e2; e_s[3][t] = e3;
        __syncthreads();

        const float bias = a_b1[t];
        float v0 = bias, v1 = bias, v2 = bias, v3 = bias;
        #pragma unroll 8
        for (int n = 0; n < H; ++n) {
            const float w = a_w1[(H + n) * H + t];
            v0 = fmaf(e_s[0][n], w, v0);
            v1 = fmaf(e_s[1][n], w, v1);
            v2 = fmaf(e_s[2][n], w, v2);
            v3 = fmaf(e_s[3][n], w, v3);
        }
        v[(f0 + 0) * H + t] = v0;
        v[(f0 + 1) * H + t] = v1;
        v[(f0 + 2) * H + t] = v2;
        v[(f0 + 3) * H + t] = v3;
    }
}

// ---------------------------------------------------------------------------
// affinity (proven 512t k-split version from rounds 6/7):
// out[r,f] = sum_k relu(u[r,k]+v[f,k])*w2[k] + b2
// 256 blocks x 512 threads (2 waves/SIMD), in-block k-split-4 + LDS reduce.
// ---------------------------------------------------------------------------
#define LDP 260

__global__ __launch_bounds__(512) void affinity_kernel(
    const float* __restrict__ u, const float* __restrict__ v,
    const float* __restrict__ a_w2, const float* __restrict__ a_b2,
    float* __restrict__ out)
{
    __shared__ float u_s[32][LDP];
    __shared__ float v_s[32][LDP];
    __shared__ float w_s[H];
    __shared__ float red[4][32][33];

    const int t  = threadIdx.x;
    const int r0 = (blockIdx.x >> 5) * 32;
    const int f0 = (blockIdx.x & 31) * 32;

    #pragma unroll
    for (int i = 0; i < 4; ++i) {
        const int slot = t + i * 512;
        const int row  = slot >> 6;
        const int cc   = (slot & 63) * 4;
        *(float4*)&u_s[row][cc] = *(const float4*)&u[(r0 + row) * H + cc];
        *(float4*)&v_s[row][cc] = *(const float4*)&v[(f0 + row) * H + cc];
    }
    if (t < 64) *(float4*)&w_s[t * 4] = *(const float4*)&a_w2[t * 4];
    __syncthreads();

    const int kp = t >> 7;
    const int t7 = t & 127;
    const int ri = t7 >> 4;
    const int fi = t7 & 15;
    const int k0 = kp * 64;

    float4 accA = make_float4(0.f, 0.f, 0.f, 0.f);
    float4 accB = make_float4(0.f, 0.f, 0.f, 0.f);

    #pragma unroll 4
    for (int kk = 0; kk < 64; kk += 4) {
        const int k = k0 + kk;
        const float4 w4 = *(const float4*)&w_s[k];
        const float4 u0 = *(const float4*)&u_s[ri][k];
        const float4 u1 = *(const float4*)&u_s[ri +  8][k];
        const float4 u2 = *(const float4*)&u_s[ri + 16][k];
        const float4 u3 = *(const float4*)&u_s[ri + 24][k];
        const float4 va = *(const float4*)&v_s[fi][k];
        const float4 vb = *(const float4*)&v_s[fi + 16][k];

        accA.x = fmaf(fmaxf(u0.x + va.x, 0.f), w4.x, accA.x);
        accA.x = fmaf(fmaxf(u0.y + va.y, 0.f), w4.y, accA.x);
        accA.x = fmaf(fmaxf(u0.z + va.z, 0.f), w4.z, accA.x);
        accA.x = fmaf(fmaxf(u0.w + va.w, 0.f), w4.w, accA.x);
        accA.y = fmaf(fmaxf(u1.x + va.x, 0.f), w4.x, accA.y);
        accA.y = fmaf(fmaxf(u1.y + va.y, 0.f), w4.y, accA.y);
        accA.y = fmaf(fmaxf(u1.z + va.z, 0.f), w4.z, accA.y);
        accA.y = fmaf(fmaxf(u1.w + va.w, 0.f), w4.w, accA.y);
        accA.z = fmaf(fmaxf(u2.x + va.x, 0.f), w4.x, accA.z);
        accA.z = fmaf(fmaxf(u2.y + va.y, 0.f), w4.y, accA.z);
        accA.z = fmaf(fmaxf(u2.z + va.z, 0.f), w4.z, accA.z);
        accA.z = fmaf(fmaxf(u2.w + va.w, 0.f), w4.w, accA.z);
        accA.w = fmaf(fmaxf(u3.x + va.x, 0.f), w4.x, accA.w);
        accA.w = fmaf(fmaxf(u3.y + va.y, 0.f), w4.y, accA.w);
        accA.w = fmaf(fmaxf(u3.z + va.z, 0.f), w4.z, accA.w);
        accA.w = fmaf(fmaxf(u3.w + va.w, 0.f), w4.w, accA.w);

        accB.x = fmaf(fmaxf(u0.x + vb.x, 0.f), w4.x, accB.x);
        accB.x = fmaf(fmaxf(u0.y + vb.y, 0.f), w4.y, accB.x);
        accB.x = fmaf(fmaxf(u0.z + vb.z, 0.f), w4.z, accB.x);
        accB.x = fmaf(fmaxf(u0.w + vb.w, 0.f), w4.w, accB.x);
        accB.y = fmaf(fmaxf(u1.x + vb.x, 0.f), w4.x, accB.y);
        accB.y = fmaf(fmaxf(u1.y + vb.y, 0.f), w4.y, accB.y);
        accB.y = fmaf(fmaxf(u1.z + vb.z, 0.f), w4.z, accB.y);
        accB.y = fmaf(fmaxf(u1.w + vb.w, 0.f), w4.w, accB.y);
        accB.z = fmaf(fmaxf(u2.x + vb.x, 0.f), w4.x, accB.z);
        accB.z = fmaf(fmaxf(u2.y + vb.y, 0.f), w4.y, accB.z);
        accB.z = fmaf(fmaxf(u2.z + vb.z, 0.f), w4.z, accB.z);
        accB.z = fmaf(fmaxf(u2.w + vb.w, 0.f), w4.w, accB.z);
        accB.w = fmaf(fmaxf(u3.x + vb.x, 0.f), w4.x, accB.w);
        accB.w = fmaf(fmaxf(u3.y + vb.y, 0.f), w4.y, accB.w);
        accB.w = fmaf(fmaxf(u3.z + vb.z, 0.f), w4.z, accB.w);
        accB.w = fmaf(fmaxf(u3.w + vb.w, 0.f), w4.w, accB.w);
    }

    red[kp][ri]     [fi]      = accA.x;
    red[kp][ri +  8][fi]      = accA.y;
    red[kp][ri + 16][fi]      = accA.z;
    red[kp][ri + 24][fi]      = accA.w;
    red[kp][ri]     [fi + 16] = accB.x;
    red[kp][ri +  8][fi + 16] = accB.y;
    red[kp][ri + 16][fi + 16] = accB.z;
    red[kp][ri + 24][fi + 16] = accB.w;
    __syncthreads();

    const float b = a_b2[0];
    #pragma unroll
    for (int j = 0; j < 2; ++j) {
        const int o = t + j * 512;
        const int r = o >> 5;
        const int f = o & 31;
        const float s = red[0][r][f] + red[1][r][f] + red[2][r][f] + red[3][r][f] + b;
        out[(r0 + r) * F_N + f0 + f] = s;
    }
}

extern "C" void kernel_launch(void* const* d_in, const int* in_sizes, int n_in,
                              void* d_out, int out_size, void* d_ws, size_t ws_size,
                              hipStream_t stream) {
    const float* rf   = (const float*)d_in[0];
    const float* ff   = (const float*)d_in[1];
    const float* r_w1 = (const float*)d_in[2];
    const float* r_b1 = (const float*)d_in[3];
    const float* r_w2 = (const float*)d_in[4];
    const float* r_b2 = (const float*)d_in[5];
    const float* f_w1 = (const float*)d_in[6];
    const float* f_b1 = (const float*)d_in[7];
    const float* f_w2 = (const float*)d_in[8];
    const float* f_b2 = (const float*)d_in[9];
    const float* a_w1 = (const float*)d_in[10];
    const float* a_b1 = (const float*)d_in[11];
    const float* a_w2 = (const float*)d_in[12];
    const float* a_b2 = (const float*)d_in[13];

    float* u = (float*)d_ws;                 // 256*256 f32
    float* v = u + R_N * H;                  // 1024*256 f32  (1.31 MB total, proven)

    embed_kernel<<<320, 256, 0, stream>>>(rf, ff, r_w1, r_b1, r_w2, r_b2,
                                          f_w1, f_b1, f_w2, f_b2,
                                          a_w1, a_b1, u, v);
    affinity_kernel<<<256, 512, 0, stream>>>(u, v, a_w2, a_b2, (float*)d_out);
}

// Round 12
// 26.109 us; speedup vs baseline: 7.1705x; 1.1341x over previous
//
#include <hip/hip_runtime.h>
#include <hip/hip_bf16.h>

#define H 256
#define R_N 256
#define F_N 1024

#define FMA4(A, s, W) \
    A.x = fmaf((s), (W).x, A.x); \
    A.y = fmaf((s), (W).y, A.y); \
    A.z = fmaf((s), (W).z, A.z); \
    A.w = fmaf((s), (W).w, A.w);

// ---------------------------------------------------------------------------
// embed v3: 4 rows/block (320 blocks — R1's proven parallelism) with R6's
// float4-weight-load + k-split-4 inner loop (4x fewer load insts, 4x bytes
// in flight). Wave wp covers k in [64wp,64wp+64); thread covers col (t&63)*4.
// Activations transposed in LDS (aT[k][0..3]) -> broadcast float4 reads.
// Cross-wave reduce via red[4][4][256].
// ---------------------------------------------------------------------------
__global__ __launch_bounds__(256) void embed_kernel(
    const float* __restrict__ rf, const float* __restrict__ ff,
    const float* __restrict__ r_w1, const float* __restrict__ r_b1,
    const float* __restrict__ r_w2, const float* __restrict__ r_b2,
    const float* __restrict__ f_w1, const float* __restrict__ f_b1,
    const float* __restrict__ f_w2, const float* __restrict__ f_b2,
    const float* __restrict__ a_w1, const float* __restrict__ a_b1,
    float* __restrict__ u, float* __restrict__ v)
{
    const int t  = threadIdx.x;
    const int wp = t >> 6;          // k-quarter (== wave id)
    const int c  = (t & 63) * 4;    // column base (float4)

    __shared__ float aT[H][4];      // transposed activations / embeddings
    __shared__ float red[4][4][H];  // cross-wave partials

    const bool robot = blockIdx.x < 64;
    const int  g0    = robot ? blockIdx.x * 4 : (blockIdx.x - 64) * 4;

    const float* __restrict__ x   = robot ? (rf + g0 * 4) : (ff + g0 * 3);
    const int                 ind = robot ? 4 : 3;
    const float* __restrict__ w1  = robot ? r_w1 : f_w1;
    const float* __restrict__ b1  = robot ? r_b1 : f_b1;
    const float* __restrict__ W2  = robot ? r_w2 : f_w2;
    const float* __restrict__ b2  = robot ? r_b2 : f_b2;
    const int                 k3  = robot ? 0 : H;   // row offset into a_w1
    float* __restrict__       dst = robot ? u : v;

    // ---- layer 1: col t for 4 rows, relu, store transposed ----
    {
        float l1[4];
        const float bb = b1[t];
        #pragma unroll
        for (int g = 0; g < 4; ++g) {
            float acc = bb;
            for (int j = 0; j < ind; ++j)
                acc = fmaf(x[g * ind + j], w1[j * H + t], acc);
            l1[g] = fmaxf(acc, 0.0f);
        }
        *(float4*)&aT[t][0] = make_float4(l1[0], l1[1], l1[2], l1[3]);
    }
    __syncthreads();

    // ---- layer 2: e = a @ W2 + b2 (float4 weights, k-split-4) ----
    {
        float4 a0 = {0,0,0,0}, a1 = {0,0,0,0}, a2 = {0,0,0,0}, a3 = {0,0,0,0};
        const int kb = wp * 64;
        #pragma unroll 8
        for (int kk = 0; kk < 64; ++kk) {
            const int k = kb + kk;
            const float4 w4 = *(const float4*)&W2[k * H + c];
            const float4 av = *(const float4*)&aT[k][0];
            FMA4(a0, av.x, w4);
            FMA4(a1, av.y, w4);
            FMA4(a2, av.z, w4);
            FMA4(a3, av.w, w4);
        }
        *(float4*)&red[wp][0][c] = a0;
        *(float4*)&red[wp][1][c] = a1;
        *(float4*)&red[wp][2][c] = a2;
        *(float4*)&red[wp][3][c] = a3;
    }
    __syncthreads();

    // ---- reduce + b2, store transposed (aliases aT safely) ----
    {
        const float bb = b2[t];
        float e[4];
        #pragma unroll
        for (int g = 0; g < 4; ++g)
            e[g] = red[0][g][t] + red[1][g][t] + red[2][g][t] + red[3][g][t] + bb;
        __syncthreads();   // all waves done reading red? (they are: reads above)
        *(float4*)&aT[t][0] = make_float4(e[0], e[1], e[2], e[3]);
    }
    __syncthreads();

    // ---- layer 3: u/v = e @ w1_{r|f} (float4 weights, k-split-4) ----
    {
        float4 a0 = {0,0,0,0}, a1 = {0,0,0,0}, a2 = {0,0,0,0}, a3 = {0,0,0,0};
        const int kb = wp * 64;
        #pragma unroll 8
        for (int kk = 0; kk < 64; ++kk) {
            const int k = kb + kk;
            const float4 w4 = *(const float4*)&a_w1[(k3 + k) * H + c];
            const float4 av = *(const float4*)&aT[k][0];
            FMA4(a0, av.x, w4);
            FMA4(a1, av.y, w4);
            FMA4(a2, av.z, w4);
            FMA4(a3, av.w, w4);
        }
        *(float4*)&red[wp][0][c] = a0;
        *(float4*)&red[wp][1][c] = a1;
        *(float4*)&red[wp][2][c] = a2;
        *(float4*)&red[wp][3][c] = a3;
    }
    __syncthreads();

    // ---- final reduce + (frontier: +a_b1) + coalesced store ----
    {
        const float ab = robot ? 0.0f : a_b1[t];
        #pragma unroll
        for (int g = 0; g < 4; ++g) {
            const float s = red[0][g][t] + red[1][g][t] + red[2][g][t] + red[3][g][t] + ab;
            dst[(g0 + g) * H + t] = s;
        }
    }
}

// ---------------------------------------------------------------------------
// affinity (byte-identical proven 512t k-split version):
// out[r,f] = sum_k relu(u[r,k]+v[f,k])*w2[k] + b2
// ---------------------------------------------------------------------------
#define LDP 260

__global__ __launch_bounds__(512) void affinity_kernel(
    const float* __restrict__ u, const float* __restrict__ v,
    const float* __restrict__ a_w2, const float* __restrict__ a_b2,
    float* __restrict__ out)
{
    __shared__ float u_s[32][LDP];
    __shared__ float v_s[32][LDP];
    __shared__ float w_s[H];
    __shared__ float red[4][32][33];

    const int t  = threadIdx.x;
    const int r0 = (blockIdx.x >> 5) * 32;
    const int f0 = (blockIdx.x & 31) * 32;

    #pragma unroll
    for (int i = 0; i < 4; ++i) {
        const int slot = t + i * 512;
        const int row  = slot >> 6;
        const int cc   = (slot & 63) * 4;
        *(float4*)&u_s[row][cc] = *(const float4*)&u[(r0 + row) * H + cc];
        *(float4*)&v_s[row][cc] = *(const float4*)&v[(f0 + row) * H + cc];
    }
    if (t < 64) *(float4*)&w_s[t * 4] = *(const float4*)&a_w2[t * 4];
    __syncthreads();

    const int kp = t >> 7;
    const int t7 = t & 127;
    const int ri = t7 >> 4;
    const int fi = t7 & 15;
    const int k0 = kp * 64;

    float4 accA = make_float4(0.f, 0.f, 0.f, 0.f);
    float4 accB = make_float4(0.f, 0.f, 0.f, 0.f);

    #pragma unroll 4
    for (int kk = 0; kk < 64; kk += 4) {
        const int k = k0 + kk;
        const float4 w4 = *(const float4*)&w_s[k];
        const float4 u0 = *(const float4*)&u_s[ri][k];
        const float4 u1 = *(const float4*)&u_s[ri +  8][k];
        const float4 u2 = *(const float4*)&u_s[ri + 16][k];
        const float4 u3 = *(const float4*)&u_s[ri + 24][k];
        const float4 va = *(const float4*)&v_s[fi][k];
        const float4 vb = *(const float4*)&v_s[fi + 16][k];

        accA.x = fmaf(fmaxf(u0.x + va.x, 0.f), w4.x, accA.x);
        accA.x = fmaf(fmaxf(u0.y + va.y, 0.f), w4.y, accA.x);
        accA.x = fmaf(fmaxf(u0.z + va.z, 0.f), w4.z, accA.x);
        accA.x = fmaf(fmaxf(u0.w + va.w, 0.f), w4.w, accA.x);
        accA.y = fmaf(fmaxf(u1.x + va.x, 0.f), w4.x, accA.y);
        accA.y = fmaf(fmaxf(u1.y + va.y, 0.f), w4.y, accA.y);
        accA.y = fmaf(fmaxf(u1.z + va.z, 0.f), w4.z, accA.y);
        accA.y = fmaf(fmaxf(u1.w + va.w, 0.f), w4.w, accA.y);
        accA.z = fmaf(fmaxf(u2.x + va.x, 0.f), w4.x, accA.z);
        accA.z = fmaf(fmaxf(u2.y + va.y, 0.f), w4.y, accA.z);
        accA.z = fmaf(fmaxf(u2.z + va.z, 0.f), w4.z, accA.z);
        accA.z = fmaf(fmaxf(u2.w + va.w, 0.f), w4.w, accA.z);
        accA.w = fmaf(fmaxf(u3.x + va.x, 0.f), w4.x, accA.w);
        accA.w = fmaf(fmaxf(u3.y + va.y, 0.f), w4.y, accA.w);
        accA.w = fmaf(fmaxf(u3.z + va.z, 0.f), w4.z, accA.w);
        accA.w = fmaf(fmaxf(u3.w + va.w, 0.f), w4.w, accA.w);

        accB.x = fmaf(fmaxf(u0.x + vb.x, 0.f), w4.x, accB.x);
        accB.x = fmaf(fmaxf(u0.y + vb.y, 0.f), w4.y, accB.x);
        accB.x = fmaf(fmaxf(u0.z + vb.z, 0.f), w4.z, accB.x);
        accB.x = fmaf(fmaxf(u0.w + vb.w, 0.f), w4.w, accB.x);
        accB.y = fmaf(fmaxf(u1.x + vb.x, 0.f), w4.x, accB.y);
        accB.y = fmaf(fmaxf(u1.y + vb.y, 0.f), w4.y, accB.y);
        accB.y = fmaf(fmaxf(u1.z + vb.z, 0.f), w4.z, accB.y);
        accB.y = fmaf(fmaxf(u1.w + vb.w, 0.f), w4.w, accB.y);
        accB.z = fmaf(fmaxf(u2.x + vb.x, 0.f), w4.x, accB.z);
        accB.z = fmaf(fmaxf(u2.y + vb.y, 0.f), w4.y, accB.z);
        accB.z = fmaf(fmaxf(u2.z + vb.z, 0.f), w4.z, accB.z);
        accB.z = fmaf(fmaxf(u2.w + vb.w, 0.f), w4.w, accB.z);
        accB.w = fmaf(fmaxf(u3.x + vb.x, 0.f), w4.x, accB.w);
        accB.w = fmaf(fmaxf(u3.y + vb.y, 0.f), w4.y, accB.w);
        accB.w = fmaf(fmaxf(u3.z + vb.z, 0.f), w4.z, accB.w);
        accB.w = fmaf(fmaxf(u3.w + vb.w, 0.f), w4.w, accB.w);
    }

    red[kp][ri]     [fi]      = accA.x;
    red[kp][ri +  8][fi]      = accA.y;
    red[kp][ri + 16][fi]      = accA.z;
    red[kp][ri + 24][fi]      = accA.w;
    red[kp][ri]     [fi + 16] = accB.x;
    red[kp][ri +  8][fi + 16] = accB.y;
    red[kp][ri + 16][fi + 16] = accB.z;
    red[kp][ri + 24][fi + 16] = accB.w;
    __syncthreads();

    const float b = a_b2[0];
    #pragma unroll
    for (int j = 0; j < 2; ++j) {
        const int o = t + j * 512;
        const int r = o >> 5;
        const int f = o & 31;
        const float s = red[0][r][f] + red[1][r][f] + red[2][r][f] + red[3][r][f] + b;
        out[(r0 + r) * F_N + f0 + f] = s;
    }
}

extern "C" void kernel_launch(void* const* d_in, const int* in_sizes, int n_in,
                              void* d_out, int out_size, void* d_ws, size_t ws_size,
                              hipStream_t stream) {
    const float* rf   = (const float*)d_in[0];
    const float* ff   = (const float*)d_in[1];
    const float* r_w1 = (const float*)d_in[2];
    const float* r_b1 = (const float*)d_in[3];
    const float* r_w2 = (const float*)d_in[4];
    const float* r_b2 = (const float*)d_in[5];
    const float* f_w1 = (const float*)d_in[6];
    const float* f_b1 = (const float*)d_in[7];
    const float* f_w2 = (const float*)d_in[8];
    const float* f_b2 = (const float*)d_in[9];
    const float* a_w1 = (const float*)d_in[10];
    const float* a_b1 = (const float*)d_in[11];
    const float* a_w2 = (const float*)d_in[12];
    const float* a_b2 = (const float*)d_in[13];

    float* u = (float*)d_ws;                 // 256*256 f32
    float* v = u + R_N * H;                  // 1024*256 f32  (1.31 MB, proven)

    embed_kernel<<<320, 256, 0, stream>>>(rf, ff, r_w1, r_b1, r_w2, r_b2,
                                          f_w1, f_b1, f_w2, f_b2,
                                          a_w1, a_b1, u, v);
    affinity_kernel<<<256, 512, 0, stream>>>(u, v, a_w2, a_b2, (float*)d_out);
}

// Round 13
// 26.014 us; speedup vs baseline: 7.1967x; 1.0037x over previous
//
#include <hip/hip_runtime.h>
#include <hip/hip_bf16.h>

#define H 256
#define R_N 256
#define F_N 1024

#define FMA4(A, s, W) \
    A.x = fmaf((s), (W).x, A.x); \
    A.y = fmaf((s), (W).y, A.y); \
    A.z = fmaf((s), (W).z, A.z); \
    A.w = fmaf((s), (W).w, A.w);

// ---------------------------------------------------------------------------
// embed (byte-identical to round-12 measured config, 26.1 us):
// 320 blocks x 256 threads, 4 rows/block, float4 weights, k-split-4.
// ---------------------------------------------------------------------------
__global__ __launch_bounds__(256) void embed_kernel(
    const float* __restrict__ rf, const float* __restrict__ ff,
    const float* __restrict__ r_w1, const float* __restrict__ r_b1,
    const float* __restrict__ r_w2, const float* __restrict__ r_b2,
    const float* __restrict__ f_w1, const float* __restrict__ f_b1,
    const float* __restrict__ f_w2, const float* __restrict__ f_b2,
    const float* __restrict__ a_w1, const float* __restrict__ a_b1,
    float* __restrict__ u, float* __restrict__ v)
{
    const int t  = threadIdx.x;
    const int wp = t >> 6;          // k-quarter (== wave id)
    const int c  = (t & 63) * 4;    // column base (float4)

    __shared__ float aT[H][4];      // transposed activations / embeddings
    __shared__ float red[4][4][H];  // cross-wave partials

    const bool robot = blockIdx.x < 64;
    const int  g0    = robot ? blockIdx.x * 4 : (blockIdx.x - 64) * 4;

    const float* __restrict__ x   = robot ? (rf + g0 * 4) : (ff + g0 * 3);
    const int                 ind = robot ? 4 : 3;
    const float* __restrict__ w1  = robot ? r_w1 : f_w1;
    const float* __restrict__ b1  = robot ? r_b1 : f_b1;
    const float* __restrict__ W2  = robot ? r_w2 : f_w2;
    const float* __restrict__ b2  = robot ? r_b2 : f_b2;
    const int                 k3  = robot ? 0 : H;   // row offset into a_w1
    float* __restrict__       dst = robot ? u : v;

    // ---- layer 1: col t for 4 rows, relu, store transposed ----
    {
        float l1[4];
        const float bb = b1[t];
        #pragma unroll
        for (int g = 0; g < 4; ++g) {
            float acc = bb;
            for (int j = 0; j < ind; ++j)
                acc = fmaf(x[g * ind + j], w1[j * H + t], acc);
            l1[g] = fmaxf(acc, 0.0f);
        }
        *(float4*)&aT[t][0] = make_float4(l1[0], l1[1], l1[2], l1[3]);
    }
    __syncthreads();

    // ---- layer 2: e = a @ W2 + b2 (float4 weights, k-split-4) ----
    {
        float4 a0 = {0,0,0,0}, a1 = {0,0,0,0}, a2 = {0,0,0,0}, a3 = {0,0,0,0};
        const int kb = wp * 64;
        #pragma unroll 8
        for (int kk = 0; kk < 64; ++kk) {
            const int k = kb + kk;
            const float4 w4 = *(const float4*)&W2[k * H + c];
            const float4 av = *(const float4*)&aT[k][0];
            FMA4(a0, av.x, w4);
            FMA4(a1, av.y, w4);
            FMA4(a2, av.z, w4);
            FMA4(a3, av.w, w4);
        }
        *(float4*)&red[wp][0][c] = a0;
        *(float4*)&red[wp][1][c] = a1;
        *(float4*)&red[wp][2][c] = a2;
        *(float4*)&red[wp][3][c] = a3;
    }
    __syncthreads();

    // ---- reduce + b2, store transposed ----
    {
        const float bb = b2[t];
        float e[4];
        #pragma unroll
        for (int g = 0; g < 4; ++g)
            e[g] = red[0][g][t] + red[1][g][t] + red[2][g][t] + red[3][g][t] + bb;
        __syncthreads();
        *(float4*)&aT[t][0] = make_float4(e[0], e[1], e[2], e[3]);
    }
    __syncthreads();

    // ---- layer 3: u/v = e @ w1_{r|f} ----
    {
        float4 a0 = {0,0,0,0}, a1 = {0,0,0,0}, a2 = {0,0,0,0}, a3 = {0,0,0,0};
        const int kb = wp * 64;
        #pragma unroll 8
        for (int kk = 0; kk < 64; ++kk) {
            const int k = kb + kk;
            const float4 w4 = *(const float4*)&a_w1[(k3 + k) * H + c];
            const float4 av = *(const float4*)&aT[k][0];
            FMA4(a0, av.x, w4);
            FMA4(a1, av.y, w4);
            FMA4(a2, av.z, w4);
            FMA4(a3, av.w, w4);
        }
        *(float4*)&red[wp][0][c] = a0;
        *(float4*)&red[wp][1][c] = a1;
        *(float4*)&red[wp][2][c] = a2;
        *(float4*)&red[wp][3][c] = a3;
    }
    __syncthreads();

    // ---- final reduce + (frontier: +a_b1) + coalesced store ----
    {
        const float ab = robot ? 0.0f : a_b1[t];
        #pragma unroll
        for (int g = 0; g < 4; ++g) {
            const float s = red[0][g][t] + red[1][g][t] + red[2][g][t] + red[3][g][t] + ab;
            dst[(g0 + g) * H + t] = s;
        }
    }
}

// ---------------------------------------------------------------------------
// affinity v3: out[r,f] = sum_k relu(u[r,k]+v[f,k])*w2[k] + b2
// 256 blocks (32x32 tiles) x 512 threads, k-split-8 (wave = one 32-k slice),
// 4x4 micro-tile per thread (rows ri+8a, cols fi+8b).
// LDS reads: 9 b128 per thread per 4-k for 16 outputs = 2.25 B/out-k
// (was 3.5) -> 590 KB/block vs 917. Broadcast-friendly: lanes sharing ri
// broadcast u rows; lanes sharing fi broadcast v rows; 8 distinct row
// addresses hit 8 distinct bank quads (stride 260 -> 4*r bank offset).
// LDS total 101 KB -> 1 block/CU (unchanged).
// ---------------------------------------------------------------------------
#define LDP 260

__global__ __launch_bounds__(512) void affinity_kernel(
    const float* __restrict__ u, const float* __restrict__ v,
    const float* __restrict__ a_w2, const float* __restrict__ a_b2,
    float* __restrict__ out)
{
    __shared__ float u_s[32][LDP];
    __shared__ float v_s[32][LDP];
    __shared__ float w_s[H];
    __shared__ float red[8][32][33];

    const int t  = threadIdx.x;
    const int r0 = (blockIdx.x >> 5) * 32;
    const int f0 = (blockIdx.x & 31) * 32;

    #pragma unroll
    for (int i = 0; i < 4; ++i) {
        const int slot = t + i * 512;
        const int row  = slot >> 6;
        const int cc   = (slot & 63) * 4;
        *(float4*)&u_s[row][cc] = *(const float4*)&u[(r0 + row) * H + cc];
        *(float4*)&v_s[row][cc] = *(const float4*)&v[(f0 + row) * H + cc];
    }
    if (t < 64) *(float4*)&w_s[t * 4] = *(const float4*)&a_w2[t * 4];
    __syncthreads();

    const int kp = t >> 6;        // wave id = k-slice 0..7
    const int t6 = t & 63;
    const int ri = t6 & 7;        // rows ri, ri+8, ri+16, ri+24
    const int fi = t6 >> 3;       // cols fi, fi+8, fi+16, fi+24
    const int k0 = kp * 32;

    float acc[4][4];
    #pragma unroll
    for (int a = 0; a < 4; ++a)
        #pragma unroll
        for (int b = 0; b < 4; ++b) acc[a][b] = 0.0f;

    #pragma unroll 4
    for (int kk = 0; kk < 32; kk += 4) {
        const int k = k0 + kk;
        const float4 w4 = *(const float4*)&w_s[k];
        float4 uu[4], vv[4];
        #pragma unroll
        for (int a = 0; a < 4; ++a) uu[a] = *(const float4*)&u_s[ri + 8 * a][k];
        #pragma unroll
        for (int b = 0; b < 4; ++b) vv[b] = *(const float4*)&v_s[fi + 8 * b][k];

        #pragma unroll
        for (int a = 0; a < 4; ++a) {
            #pragma unroll
            for (int b = 0; b < 4; ++b) {
                float s = acc[a][b];
                s = fmaf(fmaxf(uu[a].x + vv[b].x, 0.f), w4.x, s);
                s = fmaf(fmaxf(uu[a].y + vv[b].y, 0.f), w4.y, s);
                s = fmaf(fmaxf(uu[a].z + vv[b].z, 0.f), w4.z, s);
                s = fmaf(fmaxf(uu[a].w + vv[b].w, 0.f), w4.w, s);
                acc[a][b] = s;
            }
        }
    }

    // write 16 partials to LDS
    #pragma unroll
    for (int a = 0; a < 4; ++a)
        #pragma unroll
        for (int b = 0; b < 4; ++b)
            red[kp][ri + 8 * a][fi + 8 * b] = acc[a][b];
    __syncthreads();

    // reduce 8 k-partials + bias, 2 outputs per thread
    const float bb = a_b2[0];
    #pragma unroll
    for (int j = 0; j < 2; ++j) {
        const int o = t + j * 512;
        const int r = o >> 5;
        const int f = o & 31;
        float s = bb;
        #pragma unroll
        for (int q = 0; q < 8; ++q) s += red[q][r][f];
        out[(r0 + r) * F_N + f0 + f] = s;
    }
}

extern "C" void kernel_launch(void* const* d_in, const int* in_sizes, int n_in,
                              void* d_out, int out_size, void* d_ws, size_t ws_size,
                              hipStream_t stream) {
    const float* rf   = (const float*)d_in[0];
    const float* ff   = (const float*)d_in[1];
    const float* r_w1 = (const float*)d_in[2];
    const float* r_b1 = (const float*)d_in[3];
    const float* r_w2 = (const float*)d_in[4];
    const float* r_b2 = (const float*)d_in[5];
    const float* f_w1 = (const float*)d_in[6];
    const float* f_b1 = (const float*)d_in[7];
    const float* f_w2 = (const float*)d_in[8];
    const float* f_b2 = (const float*)d_in[9];
    const float* a_w1 = (const float*)d_in[10];
    const float* a_b1 = (const float*)d_in[11];
    const float* a_w2 = (const float*)d_in[12];
    const float* a_b2 = (const float*)d_in[13];

    float* u = (float*)d_ws;                 // 256*256 f32
    float* v = u + R_N * H;                  // 1024*256 f32  (1.31 MB, proven)

    embed_kernel<<<320, 256, 0, stream>>>(rf, ff, r_w1, r_b1, r_w2, r_b2,
                                          f_w1, f_b1, f_w2, f_b2,
                                          a_w1, a_b1, u, v);
    affinity_kernel<<<256, 512, 0, stream>>>(u, v, a_w2, a_b2, (float*)d_out);
}